// Round 5
// baseline (169.142 us; speedup 1.0000x reference)
//
#include <hip/hip_runtime.h>

// Binary-weight 3x3 conv via implicit GEMM on MFMA (bf16).
// out[co, p] = sum_k wb[co,k] * im2col(x)[k,p],  M=256, N=100352, K=2304.
// Round 5: counted-vmcnt quad-buffered pipeline. 72 sub-steps of BK=32;
// 4 rotating LDS buffers (A 4x16KB + B 4x14KB = 120KB); per sub-step:
// vmcnt(8)+s_barrier (never drain to 0), 11 ds_read_b128, issue stage(u+3),
// setprio(1), 28 MFMA, setprio(0). Stage-to-use distance = 3 sub-steps.

#define N_ 32
#define C_ 256
#define H_ 56
#define W_ 56
#define HP 58
#define SPATIAL (H_ * W_)          // 3136
#define P_TOTAL (N_ * SPATIAL)     // 100352
#define BNP 224
#define NBLK (P_TOTAL / BNP)       // 448
#define NSUB 72                    // 8 ci-halves * 9 taps

typedef __attribute__((ext_vector_type(8))) short short8;
typedef __attribute__((ext_vector_type(4))) float f32x4;

#define GLOAD_LDS16(g, l) __builtin_amdgcn_global_load_lds(                 \
    (const __attribute__((address_space(1))) void*)(g),                     \
    (__attribute__((address_space(3))) void*)(l), 16, 0, 0)

#define WAITV(N) asm volatile("s_waitcnt vmcnt(" #N ")" ::: "memory")
#define CFENCE() asm volatile("" ::: "memory")

__device__ inline unsigned short f2b(float f) {
    unsigned int u = __builtin_bit_cast(unsigned int, f);
    unsigned int r = (u + 0x7FFFu + ((u >> 16) & 1u)) >> 16;
    return (unsigned short)r;
}

// ---------------- prep kernels ----------------

__global__ void xform_w(const float* __restrict__ w, unsigned short* __restrict__ wt) {
    const int co = blockIdx.x;
    const int ci = threadIdx.x;
    const float* wp = w + ((size_t)co * C_ + ci) * 9;
    #pragma unroll
    for (int tap = 0; tap < 9; ++tap) {
        unsigned short v = (wp[tap] >= 0.f) ? (unsigned short)0x3F80 : (unsigned short)0xBF80;
        wt[((size_t)tap * C_ + co) * C_ + ci] = v;
    }
}

// NCHW f32 -> padded NHWC bf16 (pad value -1). Block = one (n, h) row.
__global__ __launch_bounds__(256) void xform_x(const float* __restrict__ x,
                                               unsigned short* __restrict__ xt) {
    __shared__ unsigned short lds[256][66];
    const int b = blockIdx.x;                 // n*56 + h
    const int n = b / H_;
    const int h = b - n * H_;
    const int t = threadIdx.x;
    const int wv = t & 63;
    const int wq = t >> 6;

    #pragma unroll 4
    for (int c4 = 0; c4 < 64; ++c4) {
        const int ci = c4 * 4 + wq;
        if (wv < W_)
            lds[ci][wv] = f2b(x[(((size_t)n * C_ + ci) * H_ + h) * W_ + wv]);
    }
    __syncthreads();
    unsigned short* rowp = xt + (((size_t)n * HP + h + 1) * HP) * C_;
    unsigned short* dst = rowp + C_ + t;
    for (int ww = 0; ww < W_; ++ww)
        dst[(size_t)ww * C_] = lds[t][ww];
    rowp[t] = (unsigned short)0xBF80;                       // w = 0 pad
    rowp[(size_t)57 * C_ + t] = (unsigned short)0xBF80;     // w = 57 pad
    if (h == 0) {
        unsigned short* r0  = xt + ((size_t)n * HP) * HP * C_;
        unsigned short* r57 = xt + (((size_t)n * HP + 57) * HP) * C_;
        for (int ww = 0; ww < HP; ++ww) {
            r0 [(size_t)ww * C_ + t] = (unsigned short)0xBF80;
            r57[(size_t)ww * C_ + t] = (unsigned short)0xBF80;
        }
    }
}

// ---------------- main GEMM ----------------
// grid = 448 blocks (one 224-p tile, all 256 co), 512 threads = 8 waves (4x2).
// Wave (wm,wn): 64 co x 112 p = 4x7 16x16x32 fragments, acc 112 VGPR.
// Sub-step u: cbh = u/9 (32-ci slice = cbh*32), tap = u%9 (fastest: L2/L1 reuse
// of xt). Quad LDS buffers q = u&3: A[256 rows][64B] swizzled, B[224][64B].
// Swizzle: slot col = (kc + (row>>1)) & 3  (2-way bank aliasing = free).

__global__ __launch_bounds__(512, 2) void bgemm(const unsigned short* __restrict__ xt,
                                                const unsigned short* __restrict__ wt,
                                                float* __restrict__ out) {
    extern __shared__ char smem[];
    const int t = threadIdx.x;
    const int lane = t & 63;
    const int wid = t >> 6;
    const int wm = wid >> 1;          // 0..3 (co)
    const int wn = wid & 1;           // 0..1 (p)
    const bool lowwave = (wid < 6);
    const int blk = blockIdx.x;
    const int n = blk / 14;
    const int pq = blk % 14;
    const int sp0 = pq * BNP;
    const int h0 = pq * 4;

    // ---- staging precompute (chunk c -> row = c>>2, slot = c&3, src chunk
    //      kc = (slot - (row>>1)) & 3; dest LDS byte = c*16, linear in lane) ----
    int a_off[2], x_off[2];
    #pragma unroll
    for (int i = 0; i < 2; ++i) {
        const int c = t + 512 * i;
        const int row = c >> 2;
        const int kc = ((c & 3) - (row >> 1)) & 3;
        a_off[i] = row * C_ + kc * 8;
    }
    {
        int c = t;
        int row = c >> 2;
        int kc = ((c & 3) - (row >> 1)) & 3;
        x_off[0] = ((n * HP + h0 + row / W_) * HP + (row % W_)) * C_ + kc * 8;
        c = t + 512;                       // used only when t < 384 (rows 128..223)
        row = c >> 2;
        const int rowc = (row < BNP) ? row : 0;
        kc = ((c & 3) - (row >> 1)) & 3;
        x_off[1] = ((n * HP + h0 + rowc / W_) * HP + (rowc % W_)) * C_ + kc * 8;
    }

    // ---- fragment-read precompute (byte offsets within a sub-buffer) ----
    const int g = lane >> 4;
    int aoff[4], boff[7];
    #pragma unroll
    for (int m = 0; m < 4; ++m) {
        const int r = wm * 64 + m * 16 + (lane & 15);
        aoff[m] = r * 64 + (((g + (r >> 1)) & 3) << 4);
    }
    #pragma unroll
    for (int nn = 0; nn < 7; ++nn) {
        const int r = wn * 112 + nn * 16 + (lane & 15);
        boff[nn] = r * 64 + (((g + (r >> 1)) & 3) << 4);
    }

    f32x4 acc[4][7];
    #pragma unroll
    for (int m = 0; m < 4; ++m)
        #pragma unroll
        for (int nn = 0; nn < 7; ++nn)
            acc[m][nn] = (f32x4){0.f, 0.f, 0.f, 0.f};

    auto sstage = [&](int u) {
        const int cbh = u / 9;
        const int tap = u - cbh * 9;
        const int kh = tap / 3, kw = tap - kh * 3;
        const int koff = cbh * 32;
        const int q = u & 3;
        char* Aq = smem + q * 16384;
        char* Bq = smem + 65536 + q * 14336;
        const unsigned short* asrc = wt + (size_t)tap * (C_ * C_) + koff;
        const unsigned short* bsrc = xt + (kh * HP + kw) * C_ + koff;
        GLOAD_LDS16(asrc + a_off[0], Aq + t * 16);
        GLOAD_LDS16(asrc + a_off[1], Aq + (t + 512) * 16);
        GLOAD_LDS16(bsrc + x_off[0], Bq + t * 16);
        if (t < 384)                          // wave-uniform (waves 0..5)
            GLOAD_LDS16(bsrc + x_off[1], Bq + (t + 512) * 16);
    };

    // prologue: 3 sub-steps in flight
    sstage(0); sstage(1); sstage(2);

    for (int u = 0; u < NSUB; ++u) {
        // gate: sub-step u resident (my 2 future stages may remain in flight)
        if (u < NSUB - 2)      { if (lowwave) WAITV(8); else WAITV(6); }
        else if (u == NSUB - 2){ if (lowwave) WAITV(4); else WAITV(3); }
        else                   { WAITV(0); }
        __builtin_amdgcn_s_barrier();
        CFENCE();                             // no mem op crosses above barrier

        const int q = u & 3;
        const char* Aq = smem + q * 16384;
        const char* Bq = smem + 65536 + q * 14336;
        short8 af[4], bf[7];
        #pragma unroll
        for (int m = 0; m < 4; ++m)
            af[m] = *reinterpret_cast<const short8*>(Aq + aoff[m]);
        #pragma unroll
        for (int nn = 0; nn < 7; ++nn)
            bf[nn] = *reinterpret_cast<const short8*>(Bq + boff[nn]);

        if (u < NSUB - 3) sstage(u + 3);      // overwrites buffer of u-1 (safe)

        __builtin_amdgcn_s_setprio(1);
        #pragma unroll
        for (int m = 0; m < 4; ++m)
            #pragma unroll
            for (int nn = 0; nn < 7; ++nn)
                acc[m][nn] = __builtin_amdgcn_mfma_f32_16x16x32_bf16(
                    af[m], bf[nn], acc[m][nn], 0, 0, 0);
        __builtin_amdgcn_s_setprio(0);
    }

    // epilogue: frag D col = lane&15 (p), row = (lane>>4)*4 + j (co)
    #pragma unroll
    for (int m = 0; m < 4; ++m) {
        #pragma unroll
        for (int j = 0; j < 4; ++j) {
            const int co = wm * 64 + m * 16 + (lane >> 4) * 4 + j;
            float* op = out + (size_t)(n * C_ + co) * SPATIAL + sp0 + wn * 112 + (lane & 15);
            #pragma unroll
            for (int nn = 0; nn < 7; ++nn)
                op[nn * 16] = acc[m][nn][j];
        }
    }
}

// ---------------- fallback (round-1 f32 direct conv) ----------------

__global__ __launch_bounds__(128) void bconv_f32_kernel(
    const float* __restrict__ x,
    const float* __restrict__ w,
    float* __restrict__ out)
{
    const int tx = threadIdx.x;
    const int ty = threadIdx.y;
    const int nc = blockIdx.x;
    const int co = nc & 255;
    const int h  = blockIdx.y * 8 + ty;
    const int w0 = tx * 4;
    if (tx >= 14) return;

    const float* xn = x + (size_t)(nc >> 8) * (C_ * H_ * W_);
    const float* wc = w + (size_t)co * (C_ * 9);
    float acc0 = 0.f, acc1 = 0.f, acc2 = 0.f, acc3 = 0.f;
    const bool rv0 = (h > 0), rv2 = (h < H_ - 1);
    const bool cvL = (tx != 0), cvR = (tx != 13);

    for (int ci = 0; ci < C_; ++ci) {
        const float* xc = xn + ci * (H_ * W_);
        const float* wk = wc + ci * 9;
        float v[3][6];
        #pragma unroll
        for (int r = 0; r < 3; ++r) {
            const bool rv = (r == 0) ? rv0 : (r == 2) ? rv2 : true;
            if (rv) {
                const float* rp = xc + (h + r - 1) * W_;
                const float4 m = *reinterpret_cast<const float4*>(rp + w0);
                v[r][1] = m.x; v[r][2] = m.y; v[r][3] = m.z; v[r][4] = m.w;
                v[r][0] = cvL ? rp[w0 - 1] : -1.0f;
                v[r][5] = cvR ? rp[w0 + 4] : -1.0f;
            } else {
                #pragma unroll
                for (int j = 0; j < 6; ++j) v[r][j] = -1.0f;
            }
        }
        #pragma unroll
        for (int r = 0; r < 3; ++r)
            #pragma unroll
            for (int c = 0; c < 3; ++c) {
                const float s = (wk[r * 3 + c] >= 0.f) ? 1.0f : -1.0f;
                acc0 = fmaf(s, v[r][c + 0], acc0);
                acc1 = fmaf(s, v[r][c + 1], acc1);
                acc2 = fmaf(s, v[r][c + 2], acc2);
                acc3 = fmaf(s, v[r][c + 3], acc3);
            }
    }
    float* op = out + ((size_t)nc * H_ + h) * W_ + w0;
    *reinterpret_cast<float4*>(op) = make_float4(acc0, acc1, acc2, acc3);
}

// ---------------- launch ----------------

extern "C" void kernel_launch(void* const* d_in, const int* in_sizes, int n_in,
                              void* d_out, int out_size, void* d_ws, size_t ws_size,
                              hipStream_t stream) {
    const float* x = (const float*)d_in[0];
    const float* w = (const float*)d_in[1];
    float* out = (float*)d_out;

    const size_t XT_OFF = 2u * 1024u * 1024u;
    const size_t XT_BYTES = (size_t)N_ * HP * HP * C_ * 2;
    const size_t NEEDED = XT_OFF + XT_BYTES;
    const int LDS_BYTES = 122880;   // A 4x16KB + B 4x14KB

    if (ws_size >= NEEDED) {
        unsigned short* wt = (unsigned short*)d_ws;
        unsigned short* xt = (unsigned short*)((char*)d_ws + XT_OFF);
        hipFuncSetAttribute((const void*)&bgemm,
                            hipFuncAttributeMaxDynamicSharedMemorySize, LDS_BYTES);
        xform_w<<<256, 256, 0, stream>>>(w, wt);
        xform_x<<<N_ * H_, 256, 0, stream>>>(x, xt);
        bgemm<<<NBLK, 512, LDS_BYTES, stream>>>(xt, wt, out);
    } else {
        dim3 block(16, 8);
        dim3 grid(N_ * 256, H_ / 8);
        bconv_f32_kernel<<<grid, block, 0, stream>>>(x, w, out);
    }
}

// Round 6
// 158.809 us; speedup vs baseline: 1.0651x; 1.0651x over previous
//
#include <hip/hip_runtime.h>

// Binary-weight 3x3 conv via implicit GEMM on MFMA (bf16).
// out[co, p] = sum_k wb[co,k] * im2col(x)[k,p],  M=256, N=100352, K=2304.
// Round 6: register-double-banked software pipeline. 72 sub-steps of BK=32,
// quad LDS buffers. Step u: MFMA consumes bank(u&1) (read at u-1); reads
// frags(u+1) into other bank; issues stage(u+3). vmcnt counted (never 0
// mid-loop), one barrier/step, sched_barrier fences around MFMA cluster.

#define N_ 32
#define C_ 256
#define H_ 56
#define W_ 56
#define HP 58
#define SPATIAL (H_ * W_)          // 3136
#define P_TOTAL (N_ * SPATIAL)     // 100352
#define BNP 224
#define NBLK (P_TOTAL / BNP)       // 448

typedef __attribute__((ext_vector_type(8))) short short8;
typedef __attribute__((ext_vector_type(4))) float f32x4;

#define GLOAD_LDS16(g, l) __builtin_amdgcn_global_load_lds(                 \
    (const __attribute__((address_space(1))) void*)(g),                     \
    (__attribute__((address_space(3))) void*)(l), 16, 0, 0)

#define WAITV(N) asm volatile("s_waitcnt vmcnt(" #N ")" ::: "memory")

__device__ inline unsigned short f2b(float f) {
    unsigned int u = __builtin_bit_cast(unsigned int, f);
    unsigned int r = (u + 0x7FFFu + ((u >> 16) & 1u)) >> 16;
    return (unsigned short)r;
}

// ---------------- prep kernels ----------------

__global__ void xform_w(const float* __restrict__ w, unsigned short* __restrict__ wt) {
    const int co = blockIdx.x;
    const int ci = threadIdx.x;
    const float* wp = w + ((size_t)co * C_ + ci) * 9;
    #pragma unroll
    for (int tap = 0; tap < 9; ++tap) {
        unsigned short v = (wp[tap] >= 0.f) ? (unsigned short)0x3F80 : (unsigned short)0xBF80;
        wt[((size_t)tap * C_ + co) * C_ + ci] = v;
    }
}

// NCHW f32 -> padded NHWC bf16 (pad value -1). Block = one (n, h) row.
__global__ __launch_bounds__(256) void xform_x(const float* __restrict__ x,
                                               unsigned short* __restrict__ xt) {
    __shared__ unsigned short lds[256][66];
    const int b = blockIdx.x;                 // n*56 + h
    const int n = b / H_;
    const int h = b - n * H_;
    const int t = threadIdx.x;
    const int wv = t & 63;
    const int wq = t >> 6;

    #pragma unroll 4
    for (int c4 = 0; c4 < 64; ++c4) {
        const int ci = c4 * 4 + wq;
        if (wv < W_)
            lds[ci][wv] = f2b(x[(((size_t)n * C_ + ci) * H_ + h) * W_ + wv]);
    }
    __syncthreads();
    unsigned short* rowp = xt + (((size_t)n * HP + h + 1) * HP) * C_;
    unsigned short* dst = rowp + C_ + t;
    for (int ww = 0; ww < W_; ++ww)
        dst[(size_t)ww * C_] = lds[t][ww];
    rowp[t] = (unsigned short)0xBF80;                       // w = 0 pad
    rowp[(size_t)57 * C_ + t] = (unsigned short)0xBF80;     // w = 57 pad
    if (h == 0) {
        unsigned short* r0  = xt + ((size_t)n * HP) * HP * C_;
        unsigned short* r57 = xt + (((size_t)n * HP + 57) * HP) * C_;
        for (int ww = 0; ww < HP; ++ww) {
            r0 [(size_t)ww * C_ + t] = (unsigned short)0xBF80;
            r57[(size_t)ww * C_ + t] = (unsigned short)0xBF80;
        }
    }
}

// ---------------- main GEMM ----------------
// grid = 448 blocks (XCD-swizzled), 512 threads = 8 waves (4 co x 2 p).
// Wave (wm,wn): 64 co x 112 p = 4x7 16x16x32 fragments.
// Sub-step u: cbh = u/9, tap = u%9; quad LDS buffers q = u&3.

__global__ __launch_bounds__(512, 2) void bgemm(const unsigned short* __restrict__ xt,
                                                const unsigned short* __restrict__ wt,
                                                float* __restrict__ out) {
    extern __shared__ char smem[];
    const int t = threadIdx.x;
    const int lane = t & 63;
    const int wid = t >> 6;
    const int wm = wid >> 1;          // 0..3 (co)
    const int wn = wid & 1;           // 0..1 (p)
    const bool lw = (t < 384);        // waves 0..5: 4 loads/stage, else 3
    const int bid = blockIdx.x;
    const int blk = (bid & 7) * (NBLK / 8) + (bid >> 3);   // XCD-chunked (bijective)
    const int n = blk / 14;
    const int pq = blk % 14;
    const int sp0 = pq * BNP;
    const int h0 = pq * 4;

    // ---- staging precompute (verified R5): chunk c -> row=c>>2, slot=c&3,
    //      src chunk kc=(slot-(row>>1))&3; dest byte = c*16 ----
    int a_off[2], x_off[2];
    #pragma unroll
    for (int i = 0; i < 2; ++i) {
        const int c = t + 512 * i;
        const int row = c >> 2;
        const int kc = ((c & 3) - (row >> 1)) & 3;
        a_off[i] = row * C_ + kc * 8;
    }
    {
        int c = t;
        int row = c >> 2;
        int kc = ((c & 3) - (row >> 1)) & 3;
        x_off[0] = ((n * HP + h0 + row / W_) * HP + (row % W_)) * C_ + kc * 8;
        c = t + 512;
        row = c >> 2;
        const int rowc = (row < BNP) ? row : 0;
        kc = ((c & 3) - (row >> 1)) & 3;
        x_off[1] = ((n * HP + h0 + rowc / W_) * HP + (rowc % W_)) * C_ + kc * 8;
    }

    // ---- fragment-read byte offsets (verified R5) ----
    const int g = lane >> 4;
    int aoff[4], boff[7];
    #pragma unroll
    for (int m = 0; m < 4; ++m) {
        const int r = wm * 64 + m * 16 + (lane & 15);
        aoff[m] = r * 64 + (((g + (r >> 1)) & 3) << 4);
    }
    #pragma unroll
    for (int nn = 0; nn < 7; ++nn) {
        const int r = wn * 112 + nn * 16 + (lane & 15);
        boff[nn] = r * 64 + (((g + (r >> 1)) & 3) << 4);
    }

    f32x4 acc[4][7];
    #pragma unroll
    for (int m = 0; m < 4; ++m)
        #pragma unroll
        for (int nn = 0; nn < 7; ++nn)
            acc[m][nn] = (f32x4){0.f, 0.f, 0.f, 0.f};

    auto sstage = [&](int u) {
        const int cbh = u / 9;
        const int tap = u - cbh * 9;
        const int kh = tap / 3, kw = tap - kh * 3;
        const int koff = cbh * 32;
        const int q = u & 3;
        char* Aq = smem + q * 16384;
        char* Bq = smem + 65536 + q * 14336;
        const unsigned short* asrc = wt + (size_t)tap * (C_ * C_) + koff;
        const unsigned short* bsrc = xt + (kh * HP + kw) * C_ + koff;
        GLOAD_LDS16(asrc + a_off[0], Aq + t * 16);
        GLOAD_LDS16(asrc + a_off[1], Aq + (t + 512) * 16);
        GLOAD_LDS16(bsrc + x_off[0], Bq + t * 16);
        if (lw)
            GLOAD_LDS16(bsrc + x_off[1], Bq + (t + 512) * 16);
    };

    short8 a0[4], b0[7], a1[4], b1[7];

#define READFRAGS(AF, BF, q) {                                              \
        const char* Aq_ = smem + (q) * 16384;                               \
        const char* Bq_ = smem + 65536 + (q) * 14336;                       \
        _Pragma("unroll")                                                   \
        for (int m_ = 0; m_ < 4; ++m_)                                      \
            AF[m_] = *reinterpret_cast<const short8*>(Aq_ + aoff[m_]);      \
        _Pragma("unroll")                                                   \
        for (int n_ = 0; n_ < 7; ++n_)                                      \
            BF[n_] = *reinterpret_cast<const short8*>(Bq_ + boff[n_]);      \
    }

#define MFMA28(AF, BF) {                                                    \
        __builtin_amdgcn_sched_barrier(0);                                  \
        __builtin_amdgcn_s_setprio(1);                                      \
        _Pragma("unroll")                                                   \
        for (int m_ = 0; m_ < 4; ++m_)                                      \
            _Pragma("unroll")                                               \
            for (int n_ = 0; n_ < 7; ++n_)                                  \
                acc[m_][n_] = __builtin_amdgcn_mfma_f32_16x16x32_bf16(      \
                    AF[m_], BF[n_], acc[m_][n_], 0, 0, 0);                  \
        __builtin_amdgcn_s_setprio(0);                                      \
        __builtin_amdgcn_sched_barrier(0);                                  \
    }

    // prologue: 3 stages in flight; land stage(0); read frags(0) -> bank0
    sstage(0); sstage(1); sstage(2);
    if (lw) WAITV(8); else WAITV(6);
    __builtin_amdgcn_s_barrier();
    READFRAGS(a0, b0, 0);

    for (int it = 0; it < 35; ++it) {
        const int u = 2 * it;
        // step u (even): MFMA bank0, read frags(u+1)->bank1, stage(u+3)
        if (lw) WAITV(4); else WAITV(3);
        __builtin_amdgcn_s_barrier();
        READFRAGS(a1, b1, (u + 1) & 3);
        sstage(u + 3);
        MFMA28(a0, b0);
        // step u+1 (odd): MFMA bank1, read frags(u+2)->bank0, stage(u+4)
        if (lw) WAITV(4); else WAITV(3);
        __builtin_amdgcn_s_barrier();
        READFRAGS(a0, b0, (u + 2) & 3);
        if (it < 34) sstage(u + 4);
        MFMA28(a1, b1);
    }
    // u = 70, 71
    WAITV(0);
    __builtin_amdgcn_s_barrier();
    READFRAGS(a1, b1, 3);
    MFMA28(a0, b0);
    MFMA28(a1, b1);

#undef READFRAGS
#undef MFMA28

    // epilogue: frag D col = lane&15 (p), row = (lane>>4)*4 + j (co)
    #pragma unroll
    for (int m = 0; m < 4; ++m) {
        #pragma unroll
        for (int j = 0; j < 4; ++j) {
            const int co = wm * 64 + m * 16 + (lane >> 4) * 4 + j;
            float* op = out + (size_t)(n * C_ + co) * SPATIAL + sp0 + wn * 112 + (lane & 15);
            #pragma unroll
            for (int nn = 0; nn < 7; ++nn)
                op[nn * 16] = acc[m][nn][j];
        }
    }
}

// ---------------- fallback (round-1 f32 direct conv) ----------------

__global__ __launch_bounds__(128) void bconv_f32_kernel(
    const float* __restrict__ x,
    const float* __restrict__ w,
    float* __restrict__ out)
{
    const int tx = threadIdx.x;
    const int ty = threadIdx.y;
    const int nc = blockIdx.x;
    const int co = nc & 255;
    const int h  = blockIdx.y * 8 + ty;
    const int w0 = tx * 4;
    if (tx >= 14) return;

    const float* xn = x + (size_t)(nc >> 8) * (C_ * H_ * W_);
    const float* wc = w + (size_t)co * (C_ * 9);
    float acc0 = 0.f, acc1 = 0.f, acc2 = 0.f, acc3 = 0.f;
    const bool rv0 = (h > 0), rv2 = (h < H_ - 1);
    const bool cvL = (tx != 0), cvR = (tx != 13);

    for (int ci = 0; ci < C_; ++ci) {
        const float* xc = xn + ci * (H_ * W_);
        const float* wk = wc + ci * 9;
        float v[3][6];
        #pragma unroll
        for (int r = 0; r < 3; ++r) {
            const bool rv = (r == 0) ? rv0 : (r == 2) ? rv2 : true;
            if (rv) {
                const float* rp = xc + (h + r - 1) * W_;
                const float4 m = *reinterpret_cast<const float4*>(rp + w0);
                v[r][1] = m.x; v[r][2] = m.y; v[r][3] = m.z; v[r][4] = m.w;
                v[r][0] = cvL ? rp[w0 - 1] : -1.0f;
                v[r][5] = cvR ? rp[w0 + 4] : -1.0f;
            } else {
                #pragma unroll
                for (int j = 0; j < 6; ++j) v[r][j] = -1.0f;
            }
        }
        #pragma unroll
        for (int r = 0; r < 3; ++r)
            #pragma unroll
            for (int c = 0; c < 3; ++c) {
                const float s = (wk[r * 3 + c] >= 0.f) ? 1.0f : -1.0f;
                acc0 = fmaf(s, v[r][c + 0], acc0);
                acc1 = fmaf(s, v[r][c + 1], acc1);
                acc2 = fmaf(s, v[r][c + 2], acc2);
                acc3 = fmaf(s, v[r][c + 3], acc3);
            }
    }
    float* op = out + ((size_t)nc * H_ + h) * W_ + w0;
    *reinterpret_cast<float4*>(op) = make_float4(acc0, acc1, acc2, acc3);
}

// ---------------- launch ----------------

extern "C" void kernel_launch(void* const* d_in, const int* in_sizes, int n_in,
                              void* d_out, int out_size, void* d_ws, size_t ws_size,
                              hipStream_t stream) {
    const float* x = (const float*)d_in[0];
    const float* w = (const float*)d_in[1];
    float* out = (float*)d_out;

    const size_t XT_OFF = 2u * 1024u * 1024u;
    const size_t XT_BYTES = (size_t)N_ * HP * HP * C_ * 2;
    const size_t NEEDED = XT_OFF + XT_BYTES;
    const int LDS_BYTES = 122880;   // A 4x16KB + B 4x14KB

    if (ws_size >= NEEDED) {
        unsigned short* wt = (unsigned short*)d_ws;
        unsigned short* xt = (unsigned short*)((char*)d_ws + XT_OFF);
        hipFuncSetAttribute((const void*)&bgemm,
                            hipFuncAttributeMaxDynamicSharedMemorySize, LDS_BYTES);
        xform_w<<<256, 256, 0, stream>>>(w, wt);
        xform_x<<<N_ * H_, 256, 0, stream>>>(x, xt);
        bgemm<<<NBLK, 512, LDS_BYTES, stream>>>(xt, wt, out);
    } else {
        dim3 block(16, 8);
        dim3 grid(N_ * 256, H_ / 8);
        bconv_f32_kernel<<<grid, block, 0, stream>>>(x, w, out);
    }
}

// Round 7
// 105.248 us; speedup vs baseline: 1.6071x; 1.5089x over previous
//
#include <hip/hip_runtime.h>

// Binary-weight 3x3 conv via implicit GEMM on int8 MFMA.
// out[co, p] = (1/26) * sum_k wb[co,k] * q26(im2col(x))[k,p],  exact i32 accum.
// Round 7: i8 port of the R6 pipeline. 36 sub-steps of BK=64(ci), quad LDS
// buffers (A 4x16KB + B 4x14KB), reg-double-banked MFMA, counted vmcnt.
// Byte geometry (64B rows, 4x16B swizzled slots) identical to verified R6.

#define N_ 32
#define C_ 256
#define H_ 56
#define W_ 56
#define HP 58
#define SPATIAL (H_ * W_)          // 3136
#define P_TOTAL (N_ * SPATIAL)     // 100352
#define BNP 224
#define NBLK (P_TOTAL / BNP)       // 448
#define NSUB 36                    // 4 ci-slices(64) * 9 taps
#define QSCALE 26.0f
#define QINV (1.0f / 26.0f)

typedef __attribute__((ext_vector_type(4))) int int32x4;

#define GLOAD_LDS16(g, l) __builtin_amdgcn_global_load_lds(                 \
    (const __attribute__((address_space(1))) void*)(g),                     \
    (__attribute__((address_space(3))) void*)(l), 16, 0, 0)

#define WAITV(N) asm volatile("s_waitcnt vmcnt(" #N ")" ::: "memory")

// ---------------- prep kernels ----------------

__global__ void xform_w(const float* __restrict__ w, char* __restrict__ wt) {
    const int co = blockIdx.x;
    const int ci = threadIdx.x;
    const float* wp = w + ((size_t)co * C_ + ci) * 9;
    #pragma unroll
    for (int tap = 0; tap < 9; ++tap)
        wt[((size_t)tap * C_ + co) * C_ + ci] = (wp[tap] >= 0.f) ? (char)1 : (char)-1;
}

// NCHW f32 -> padded NHWC i8 (q = clamp(rint(26x)); pad = -26). Block = (n,h).
__global__ __launch_bounds__(256) void xform_x(const float* __restrict__ x,
                                               unsigned char* __restrict__ xt) {
    __shared__ unsigned char lds8[64 * 272];   // [w][ci], stride 272 (16-mult)
    const int b = blockIdx.x;                  // n*56 + h
    const int n = b / H_;
    const int h = b - n * H_;
    const int t = threadIdx.x;
    const int wq = t >> 6;                     // ci quarter
    const int wv = t & 63;                     // w lane
    const float* xp = x + (((size_t)n * C_ + wq * 64) * H_ + h) * W_ + wv;

    #pragma unroll 4
    for (int c4 = 0; c4 < 64; c4 += 4) {
        unsigned int pk = 0;
        #pragma unroll
        for (int j = 0; j < 4; ++j) {
            float v = (wv < W_) ? xp[(size_t)(c4 + j) * SPATIAL] : 0.f;
            int q = (int)rintf(v * QSCALE);
            q = q < -127 ? -127 : (q > 127 ? 127 : q);
            pk |= ((unsigned int)(q & 255)) << (8 * j);
        }
        if (wv < W_)
            *reinterpret_cast<unsigned int*>(&lds8[wv * 272 + wq * 64 + c4]) = pk;
    }
    __syncthreads();

    unsigned char* rowp = xt + (((size_t)n * HP + h + 1) * HP) * C_;
    {   // interior: w = 1..56, 64B (4x16B) per thread along ci
        const int ww = t & 63, cq = t >> 6;
        if (ww < W_) {
            #pragma unroll
            for (int j = 0; j < 4; ++j) {
                int32x4 v = *reinterpret_cast<const int32x4*>(
                    &lds8[ww * 272 + cq * 64 + j * 16]);
                *reinterpret_cast<int32x4*>(rowp + (size_t)(ww + 1) * C_ + cq * 64 + j * 16) = v;
            }
        }
    }
    if (t < 64) {   // pad cols w=0 and w=57 (0xE6 = -26)
        reinterpret_cast<unsigned int*>(rowp)[t] = 0xE6E6E6E6u;
        reinterpret_cast<unsigned int*>(rowp + (size_t)57 * C_)[t] = 0xE6E6E6E6u;
    }
    if (h == 0) {   // pad rows 0 and 57 once per n
        unsigned int* r0  = reinterpret_cast<unsigned int*>(xt + ((size_t)n * HP) * HP * C_);
        unsigned int* r57 = reinterpret_cast<unsigned int*>(xt + (((size_t)n * HP + 57) * HP) * C_);
        for (int idx = t; idx < HP * C_ / 4; idx += 256) {
            r0[idx]  = 0xE6E6E6E6u;
            r57[idx] = 0xE6E6E6E6u;
        }
    }
}

// ---------------- main GEMM ----------------
// grid = 448 blocks (XCD-swizzled), 512 threads = 8 waves (4 co x 2 p).
// Wave (wm,wn): 64 co x 112 p = 4x7 16x16x64 i8 fragments.
// Sub-step u: cbh = u/9 (64-ci slice), tap = u%9; quad LDS buffers q = u&3.

__global__ __launch_bounds__(512, 2) void bgemm(const unsigned char* __restrict__ xt,
                                                const unsigned char* __restrict__ wt,
                                                float* __restrict__ out) {
    extern __shared__ char smem[];
    const int t = threadIdx.x;
    const int lane = t & 63;
    const int wid = t >> 6;
    const int wm = wid >> 1;          // 0..3 (co)
    const int wn = wid & 1;           // 0..1 (p)
    const bool lw = (t < 384);        // waves 0..5: 4 loads/stage, else 3
    const int bid = blockIdx.x;
    const int blk = (bid & 7) * (NBLK / 8) + (bid >> 3);   // XCD-chunked (bijective)
    const int n = blk / 14;
    const int pq = blk % 14;
    const int sp0 = pq * BNP;
    const int h0 = pq * 4;

    // staging: chunk c -> row=c>>2, slot=c&3, src chunk kc=(slot-(row>>1))&3.
    // offsets in BYTES (row stride = C_ = 256 B, 64B staged per row).
    int a_off[2], x_off[2];
    #pragma unroll
    for (int i = 0; i < 2; ++i) {
        const int c = t + 512 * i;
        const int row = c >> 2;
        const int kc = ((c & 3) - (row >> 1)) & 3;
        a_off[i] = row * C_ + kc * 16;
    }
    {
        int c = t;
        int row = c >> 2;
        int kc = ((c & 3) - (row >> 1)) & 3;
        x_off[0] = ((n * HP + h0 + row / W_) * HP + (row % W_)) * C_ + kc * 16;
        c = t + 512;
        row = c >> 2;
        const int rowc = (row < BNP) ? row : 0;
        kc = ((c & 3) - (row >> 1)) & 3;
        x_off[1] = ((n * HP + h0 + rowc / W_) * HP + (rowc % W_)) * C_ + kc * 16;
    }

    // fragment-read byte offsets (same verified scheme: 64B rows, slot=(g+(r>>1))&3)
    const int g = lane >> 4;
    int aoff[4], boff[7];
    #pragma unroll
    for (int m = 0; m < 4; ++m) {
        const int r = wm * 64 + m * 16 + (lane & 15);
        aoff[m] = r * 64 + (((g + (r >> 1)) & 3) << 4);
    }
    #pragma unroll
    for (int nn = 0; nn < 7; ++nn) {
        const int r = wn * 112 + nn * 16 + (lane & 15);
        boff[nn] = r * 64 + (((g + (r >> 1)) & 3) << 4);
    }

    int32x4 acc[4][7];
    #pragma unroll
    for (int m = 0; m < 4; ++m)
        #pragma unroll
        for (int nn = 0; nn < 7; ++nn)
            acc[m][nn] = (int32x4){0, 0, 0, 0};

    auto sstage = [&](int u) {
        const int cbh = u / 9;
        const int tap = u - cbh * 9;
        const int kh = tap / 3, kw = tap - kh * 3;
        const int koff = cbh * 64;
        const int q = u & 3;
        char* Aq = smem + q * 16384;
        char* Bq = smem + 65536 + q * 14336;
        const unsigned char* asrc = wt + (size_t)tap * (C_ * C_) + koff;
        const unsigned char* bsrc = xt + (kh * HP + kw) * C_ + koff;
        GLOAD_LDS16(asrc + a_off[0], Aq + t * 16);
        GLOAD_LDS16(asrc + a_off[1], Aq + (t + 512) * 16);
        GLOAD_LDS16(bsrc + x_off[0], Bq + t * 16);
        if (lw)
            GLOAD_LDS16(bsrc + x_off[1], Bq + (t + 512) * 16);
    };

    int32x4 a0[4], b0[7], a1[4], b1[7];

#define READFRAGS(AF, BF, q) {                                              \
        const char* Aq_ = smem + (q) * 16384;                               \
        const char* Bq_ = smem + 65536 + (q) * 14336;                       \
        _Pragma("unroll")                                                   \
        for (int m_ = 0; m_ < 4; ++m_)                                      \
            AF[m_] = *reinterpret_cast<const int32x4*>(Aq_ + aoff[m_]);     \
        _Pragma("unroll")                                                   \
        for (int n_ = 0; n_ < 7; ++n_)                                      \
            BF[n_] = *reinterpret_cast<const int32x4*>(Bq_ + boff[n_]);     \
    }

#define MFMA28(AF, BF) {                                                    \
        __builtin_amdgcn_sched_barrier(0);                                  \
        __builtin_amdgcn_s_setprio(1);                                      \
        _Pragma("unroll")                                                   \
        for (int m_ = 0; m_ < 4; ++m_)                                      \
            _Pragma("unroll")                                               \
            for (int n_ = 0; n_ < 7; ++n_)                                  \
                acc[m_][n_] = __builtin_amdgcn_mfma_i32_16x16x64_i8(        \
                    AF[m_], BF[n_], acc[m_][n_], 0, 0, 0);                  \
        __builtin_amdgcn_s_setprio(0);                                      \
        __builtin_amdgcn_sched_barrier(0);                                  \
    }

    // prologue: 3 stages in flight; land stage(0); read frags(0) -> bank0
    sstage(0); sstage(1); sstage(2);
    if (lw) WAITV(8); else WAITV(6);
    __builtin_amdgcn_s_barrier();
    READFRAGS(a0, b0, 0);

    for (int it = 0; it < 17; ++it) {
        const int u = 2 * it;
        // even step u: MFMA bank0 (frags u), read frags(u+1)->bank1, stage(u+3)
        if (lw) WAITV(4); else WAITV(3);
        __builtin_amdgcn_s_barrier();
        READFRAGS(a1, b1, (u + 1) & 3);
        sstage(u + 3);
        MFMA28(a0, b0);
        // odd step u+1: MFMA bank1, read frags(u+2)->bank0, stage(u+4)
        if (lw) WAITV(4); else WAITV(3);
        __builtin_amdgcn_s_barrier();
        READFRAGS(a0, b0, (u + 2) & 3);
        if (it < 16) sstage(u + 4);
        MFMA28(a1, b1);
    }
    // u = 34, 35
    WAITV(0);
    __builtin_amdgcn_s_barrier();
    READFRAGS(a1, b1, 3);
    MFMA28(a0, b0);
    MFMA28(a1, b1);

#undef READFRAGS
#undef MFMA28

    // epilogue: D col = lane&15 (p), row = (lane>>4)*4 + j (co); scale by 1/26
    #pragma unroll
    for (int m = 0; m < 4; ++m) {
        #pragma unroll
        for (int j = 0; j < 4; ++j) {
            const int co = wm * 64 + m * 16 + (lane >> 4) * 4 + j;
            float* op = out + (size_t)(n * C_ + co) * SPATIAL + sp0 + wn * 112 + (lane & 15);
            #pragma unroll
            for (int nn = 0; nn < 7; ++nn)
                op[nn * 16] = (float)acc[m][nn][j] * QINV;
        }
    }
}

// ---------------- fallback (round-1 f32 direct conv) ----------------

__global__ __launch_bounds__(128) void bconv_f32_kernel(
    const float* __restrict__ x,
    const float* __restrict__ w,
    float* __restrict__ out)
{
    const int tx = threadIdx.x;
    const int ty = threadIdx.y;
    const int nc = blockIdx.x;
    const int co = nc & 255;
    const int h  = blockIdx.y * 8 + ty;
    const int w0 = tx * 4;
    if (tx >= 14) return;

    const float* xn = x + (size_t)(nc >> 8) * (C_ * H_ * W_);
    const float* wc = w + (size_t)co * (C_ * 9);
    float acc0 = 0.f, acc1 = 0.f, acc2 = 0.f, acc3 = 0.f;
    const bool rv0 = (h > 0), rv2 = (h < H_ - 1);
    const bool cvL = (tx != 0), cvR = (tx != 13);

    for (int ci = 0; ci < C_; ++ci) {
        const float* xc = xn + ci * (H_ * W_);
        const float* wk = wc + ci * 9;
        float v[3][6];
        #pragma unroll
        for (int r = 0; r < 3; ++r) {
            const bool rv = (r == 0) ? rv0 : (r == 2) ? rv2 : true;
            if (rv) {
                const float* rp = xc + (h + r - 1) * W_;
                const float4 m = *reinterpret_cast<const float4*>(rp + w0);
                v[r][1] = m.x; v[r][2] = m.y; v[r][3] = m.z; v[r][4] = m.w;
                v[r][0] = cvL ? rp[w0 - 1] : -1.0f;
                v[r][5] = cvR ? rp[w0 + 4] : -1.0f;
            } else {
                #pragma unroll
                for (int j = 0; j < 6; ++j) v[r][j] = -1.0f;
            }
        }
        #pragma unroll
        for (int r = 0; r < 3; ++r)
            #pragma unroll
            for (int c = 0; c < 3; ++c) {
                const float s = (wk[r * 3 + c] >= 0.f) ? 1.0f : -1.0f;
                acc0 = fmaf(s, v[r][c + 0], acc0);
                acc1 = fmaf(s, v[r][c + 1], acc1);
                acc2 = fmaf(s, v[r][c + 2], acc2);
                acc3 = fmaf(s, v[r][c + 3], acc3);
            }
    }
    float* op = out + ((size_t)nc * H_ + h) * W_ + w0;
    *reinterpret_cast<float4*>(op) = make_float4(acc0, acc1, acc2, acc3);
}

// ---------------- launch ----------------

extern "C" void kernel_launch(void* const* d_in, const int* in_sizes, int n_in,
                              void* d_out, int out_size, void* d_ws, size_t ws_size,
                              hipStream_t stream) {
    const float* x = (const float*)d_in[0];
    const float* w = (const float*)d_in[1];
    float* out = (float*)d_out;

    const size_t XT_OFF = 2u * 1024u * 1024u;                 // wt region (590KB)
    const size_t XT_BYTES = (size_t)N_ * HP * HP * C_;        // 27,557,888 (i8)
    const size_t NEEDED = XT_OFF + XT_BYTES;
    const int LDS_BYTES = 122880;   // A 4x16KB + B 4x14KB

    if (ws_size >= NEEDED) {
        char* wt = (char*)d_ws;
        unsigned char* xt = (unsigned char*)((char*)d_ws + XT_OFF);
        hipFuncSetAttribute((const void*)&bgemm,
                            hipFuncAttributeMaxDynamicSharedMemorySize, LDS_BYTES);
        xform_w<<<256, 256, 0, stream>>>(w, wt);
        xform_x<<<N_ * H_, 256, 0, stream>>>(x, xt);
        bgemm<<<NBLK, 512, LDS_BYTES, stream>>>(xt, (const unsigned char*)wt, out);
    } else {
        dim3 block(16, 8);
        dim3 grid(N_ * 256, H_ / 8);
        bconv_f32_kernel<<<grid, block, 0, stream>>>(x, w, out);
    }
}